// Round 7
// baseline (354.933 us; speedup 1.0000x reference)
//
#include <hip/hip_runtime.h>
#include <stdint.h>

#define ROUNDS 64
#define HIDDEN 256
#define BATCH  65536

typedef int   v4i  __attribute__((ext_vector_type(4)));
typedef int   v8i  __attribute__((ext_vector_type(8)));
typedef float v16f __attribute__((ext_vector_type(16)));

// ws layout: Wpk fp4 fragments [r][mt=8][ks=4][lane=64][16B] = 2 MB,
// then noise masks u32 [r][i=4][lh=2][w=4] = 8 KB.
#define WPK_BYTES (ROUNDS * 8 * 4 * 64 * 16)

// sigma: nibble slot n (0..31) within a 32-k chunk holds logical k-offset
// rho(n). Rows (j&3)+8*(j>>2)+4*lh of the 32x32 C layout land in each lane's
// own contiguous 8 bytes -> 1 conflict-free ds_write_b64 per tile. Applied
// identically to W-pack, state init, and unpack, so it cancels in the dot.
__host__ __device__ constexpr int rho(int n) {
  return 4 * (n >> 4) + (n & 3) + 8 * ((n >> 2) & 3);
}

// ---- pack W into fp4 A-fragments (blocks 0..511); noise -> packed-nibble
// XOR masks (blocks 512..519): nm[r][i][lh][di*2+half] has bit 4*jj+1 set if
// noise[r][(2i+di)*32 + (j&3)+8*(j>>2)+4*lh] != 0, j = half*8+jj. ----
__global__ __launch_bounds__(256) void pack_w4(const float* __restrict__ mat,
                                               const float* __restrict__ noi,
                                               uint32_t* __restrict__ wpk,
                                               uint32_t* __restrict__ nm) {
  if (blockIdx.x >= 512) {
    unsigned tg = (blockIdx.x - 512) * 256u + threadIdx.x;  // < 2048
    unsigned w = tg & 3u, lh = (tg >> 2) & 1u, ii = (tg >> 3) & 3u, r = tg >> 5;
    unsigned di = w >> 1, half = w & 1u, mt = 2u * ii + di;
    const float* np = noi + r * 256u + mt * 32u + 4u * lh;
    uint32_t m = 0;
#pragma unroll
    for (int jj = 0; jj < 8; ++jj) {
      int jf = (int)half * 8 + jj;
      int row = (jf & 3) + 8 * (jf >> 2);
      if (np[row] != 0.0f) m |= 1u << (4 * jj + 1);
    }
    nm[tg] = m;
    return;
  }
  unsigned tg = blockIdx.x * 256u + threadIdx.x;  // (r*256+row)*8 + kwin
  unsigned kwin = tg & 7u;
  unsigned rr = tg >> 3;  // r*256 + row
  const float4* F4 = (const float4*)(mat + (size_t)rr * 256 + kwin * 32);
  float4 F[8];
#pragma unroll
  for (int i = 0; i < 8; ++i) F[i] = F4[i];
  const float* Ff = (const float*)F;
  uint32_t w[4] = {0, 0, 0, 0};
#pragma unroll
  for (int n = 0; n < 32; ++n) {
    uint32_t u = __builtin_bit_cast(uint32_t, Ff[rho(n)]);
    // fp4 e2m1: 0 -> 0b0000, +1 -> 0b0010, -1 -> 0b1010
    uint32_t nib = ((u & 0x7fffffffu) ? 2u : 0u) | ((u >> 28) & 8u);
    w[n >> 3] |= nib << ((n & 7) * 4);
  }
  unsigned r = rr >> 8, row = rr & 255u;
  unsigned mt = row >> 5, lh = kwin & 1u, ks = kwin >> 1;
  unsigned lane = lh * 32u + (row & 31u);
  *(uint4*)(wpk + ((((r * 8u + mt) * 4u + ks) * 64u + lane) << 2)) =
      make_uint4(w[0], w[1], w[2], w[3]);
}

// ---- main: 128 el/block, 8 waves. Wave (i=wv>>1, j=wv&1): m-tiles {2i,2i+1}
// x element-half j (halves the LDS B-reads vs all-el waves). acc accumulates
// across ALL rounds (never reset; |acc| <= 64*256 exact in f32); round bit =
// parity(acc_r) ^ parity(acc_{r-1}) ^ noise — parity telescoping kills the
// per-round C-init. Upper halves of fp4 A/B tuples are undef (HW ignores
// regs 4-7 for fmt=fp4) — no zero-fill movs. ----
__global__ __launch_bounds__(512, 4) void hash4(const uint32_t* __restrict__ wpk,
                                                const uint32_t* __restrict__ nm,
                                                const float* __restrict__ sta,
                                                float* __restrict__ out) {
  __shared__ uint8_t T[2][8][128][16];  // 32 KB, [buf][kb][el][16B chunk]
  const int t = threadIdx.x;
  const int wv = __builtin_amdgcn_readfirstlane(t >> 6);
  const int i = wv >> 1, j = wv & 1;
  const int lane = t & 63, l31 = lane & 31, lh = lane >> 5;
  const int el0 = blockIdx.x * 128;

  // ---- initial pack: f32 -> sigma-ordered fp4 nibbles (4 logical k per u16) ----
#pragma unroll
  for (int it = 0; it < 16; ++it) {
    unsigned flat = (unsigned)it * 512u + t;  // float4 idx in 128x256 slab
    unsigned el = flat >> 6, k4 = flat & 63u;
    float4 f = ((const float4*)(sta + (size_t)el0 * 256))[flat];
    uint32_t v = ((f.x != 0.f) ? 0x2u : 0u) | ((f.y != 0.f) ? 0x20u : 0u) |
                 ((f.z != 0.f) ? 0x200u : 0u) | ((f.w != 0.f) ? 0x2000u : 0u);
    unsigned KB = k4 >> 3, k4c = k4 & 7u;
    unsigned byteoff = (k4c & 1u) * 8u + 2u * (k4c >> 1);  // sigma^-1 of 4 rows
    *(uint16_t*)&T[0][KB][el][byteoff] = (uint16_t)v;
  }
  __syncthreads();

  const v4i* Wv = (const v4i*)wpk;        // [((r*8+mt)*4+ks)*64 + lane]
  const uint4* NMp = (const uint4*)nm;    // [(r*4+i)*2+lh]

  v16f acc[2][2] = {};                    // [di][tn], cumulative, AGPR-resident
  uint32_t plo[2][2] = {}, phi[2][2] = {};

  auto body = [&](int R, int SRC, int DST) __attribute__((always_inline)) {
    uint4 nmv = NMp[(R * 4 + i) * 2 + lh];
#pragma unroll
    for (int ks = 0; ks < 4; ++ks) {
      v4i a0 = Wv[((R * 8 + 2 * i) * 4 + ks) * 64 + lane];
      v4i a1 = Wv[((R * 8 + 2 * i + 1) * 4 + ks) * 64 + lane];
      int kb = 2 * ks + lh;
      v4i b0 = *(const v4i*)&T[SRC][kb][j * 64 + l31][0];
      v4i b1 = *(const v4i*)&T[SRC][kb][j * 64 + 32 + l31][0];
      v8i A0 = __builtin_shufflevector(a0, a0, 0, 1, 2, 3, -1, -1, -1, -1);
      v8i A1 = __builtin_shufflevector(a1, a1, 0, 1, 2, 3, -1, -1, -1, -1);
      v8i B0 = __builtin_shufflevector(b0, b0, 0, 1, 2, 3, -1, -1, -1, -1);
      v8i B1 = __builtin_shufflevector(b1, b1, 0, 1, 2, 3, -1, -1, -1, -1);
      acc[0][0] = __builtin_amdgcn_mfma_scale_f32_32x32x64_f8f6f4(
          A0, B0, acc[0][0], 4, 4, 0, 127, 0, 127);
      acc[0][1] = __builtin_amdgcn_mfma_scale_f32_32x32x64_f8f6f4(
          A0, B1, acc[0][1], 4, 4, 0, 127, 0, 127);
      acc[1][0] = __builtin_amdgcn_mfma_scale_f32_32x32x64_f8f6f4(
          A1, B0, acc[1][0], 4, 4, 0, 127, 0, 127);
      acc[1][1] = __builtin_amdgcn_mfma_scale_f32_32x32x64_f8f6f4(
          A1, B1, acc[1][1], 4, 4, 0, 127, 0, 127);
    }
    // epilogue: parity of cumulative acc via bias trick (LSB at bit 1 since
    // acc+1.5*2^22 in [2^22,2^23), |acc|<=16448); telescoped XOR vs last round.
#pragma unroll
    for (int di = 0; di < 2; ++di) {
      uint32_t nlo = di ? nmv.z : nmv.x, nhi = di ? nmv.w : nmv.y;
#pragma unroll
      for (int tn = 0; tn < 2; ++tn) {
        uint32_t lo = 0, hi = 0;
#pragma unroll
        for (int jj = 7; jj >= 0; --jj)
          lo = (lo << 4) |
               (__builtin_bit_cast(uint32_t, acc[di][tn][jj] + 6291456.0f) & 2u);
#pragma unroll
        for (int jj = 15; jj >= 8; --jj)
          hi = (hi << 4) |
               (__builtin_bit_cast(uint32_t, acc[di][tn][jj] + 6291456.0f) & 2u);
        uint32_t olo = lo ^ plo[di][tn] ^ nlo;
        uint32_t ohi = hi ^ phi[di][tn] ^ nhi;
        plo[di][tn] = lo;
        phi[di][tn] = hi;
        *(uint2*)&T[DST][2 * i + di][j * 64 + tn * 32 + l31][lh * 8] =
            make_uint2(olo, ohi);
      }
    }
    __syncthreads();  // single barrier/round (double-buffered state)
  };

  for (int r = 0; r < ROUNDS; r += 2) {
    body(r, 0, 1);
    body(r + 1, 1, 0);
  }

  // ---- final unpack: buf 0 holds the round-63 output ----
#pragma unroll
  for (int it = 0; it < 16; ++it) {
    unsigned flat = (unsigned)it * 512u + t;
    unsigned el = flat >> 6, k4 = flat & 63u;
    unsigned KB = k4 >> 3, k4c = k4 & 7u;
    unsigned byteoff = (k4c & 1u) * 8u + 2u * (k4c >> 1);
    uint32_t v = *(const uint16_t*)&T[0][KB][el][byteoff];
    float4 o = make_float4((float)((v >> 1) & 1u), (float)((v >> 5) & 1u),
                           (float)((v >> 9) & 1u), (float)((v >> 13) & 1u));
    ((float4*)(out + (size_t)el0 * 256))[flat] = o;
  }
}

extern "C" void kernel_launch(void* const* d_in, const int* in_sizes, int n_in,
                              void* d_out, int out_size, void* d_ws, size_t ws_size,
                              hipStream_t stream) {
  const float* sta = (const float*)d_in[0];  // [B, HIDDEN]
  const float* mat = (const float*)d_in[1];  // [ROUNDS, HIDDEN, HIDDEN]
  const float* noi = (const float*)d_in[2];  // [ROUNDS, HIDDEN]
  uint8_t* wsb = (uint8_t*)d_ws;             // needs ~2.01 MB

  pack_w4<<<520, 256, 0, stream>>>(mat, noi, (uint32_t*)wsb,
                                   (uint32_t*)(wsb + WPK_BYTES));
  hash4<<<512, 512, 0, stream>>>((const uint32_t*)wsb,
                                 (const uint32_t*)(wsb + WPK_BYTES), sta,
                                 (float*)d_out);
}

// Round 10
// 300.769 us; speedup vs baseline: 1.1801x; 1.1801x over previous
//
#include <hip/hip_runtime.h>
#include <stdint.h>

#define ROUNDS 64
#define HIDDEN 256
#define BATCH  65536

typedef int   v4i  __attribute__((ext_vector_type(4)));
typedef int   v8i  __attribute__((ext_vector_type(8)));
typedef float v16f __attribute__((ext_vector_type(16)));

// ws layout: Wpk fp4 fragments [r][mt=8][ks=4][lane=64][16B] = 2 MB,
// then noise floats [r][wv=8][lh=2][j=16] f32 = 64 KB.
#define WPK_BYTES (ROUNDS * 8 * 4 * 64 * 16)

// sigma: nibble slot n (0..31) within a 32-k chunk holds logical k-offset
// rho(n). Rows (j&3)+8*(j>>2)+4*lh of the 32x32 C layout land in each lane's
// own contiguous 8 bytes -> 1 conflict-free ds_write_b64 epilogue. Applied
// identically to W-pack, state init, and unpack, so it cancels in the dot.
__host__ __device__ constexpr int rho(int n) {
  return 4 * (n >> 4) + (n & 3) + 8 * ((n >> 2) & 3);
}

// ---- pack W into fp4 A-fragments (blocks 0..511) and noise->f32 in
// C-layout row order (blocks 512..575) ----
__global__ __launch_bounds__(256) void pack_w4(const float* __restrict__ mat,
                                               const float* __restrict__ noi,
                                               uint32_t* __restrict__ wpk,
                                               float* __restrict__ nf) {
  if (blockIdx.x >= 512) {  // noise: nf[r][wv][lh][j] = noise[r][row(j,lh)+wv*32]
    unsigned tg = (blockIdx.x - 512) * 256u + threadIdx.x;  // < 16384
    unsigned j = tg & 15u, lh = (tg >> 4) & 1u, wv = (tg >> 5) & 7u, r = tg >> 8;
    unsigned row = wv * 32u + (j & 3u) + 8u * (j >> 2) + 4u * lh;
    nf[tg] = noi[r * 256u + row];
    return;
  }
  unsigned tg = blockIdx.x * 256u + threadIdx.x;  // (r*256+row)*8 + kwin
  unsigned kwin = tg & 7u;
  unsigned rr = tg >> 3;  // r*256 + row
  const float4* F4 = (const float4*)(mat + (size_t)rr * 256 + kwin * 32);
  float4 F[8];
#pragma unroll
  for (int i = 0; i < 8; ++i) F[i] = F4[i];
  const float* Ff = (const float*)F;
  uint32_t w[4] = {0, 0, 0, 0};
#pragma unroll
  for (int n = 0; n < 32; ++n) {
    uint32_t u = __builtin_bit_cast(uint32_t, Ff[rho(n)]);
    // fp4 e2m1: 0 -> 0b0000, +1 -> 0b0010, -1 -> 0b1010
    uint32_t nib = ((u & 0x7fffffffu) ? 2u : 0u) | ((u >> 28) & 8u);
    w[n >> 3] |= nib << ((n & 7) * 4);
  }
  unsigned r = rr >> 8, row = rr & 255u;
  unsigned mt = row >> 5, lh = kwin & 1u, ks = kwin >> 1;
  unsigned lane = lh * 32u + (row & 31u);
  *(uint4*)(wpk + ((((r * 8u + mt) * 4u + ks) * 64u + lane) << 2)) =
      make_uint4(w[0], w[1], w[2], w[3]);
}

// ---- main: 128 el/block, 8 waves; wave wv = rows [wv*32, wv*32+32) for all
// 128 elements. fp4 MFMA 32x32x64, K=256 in 4 steps, noise as MFMA C-init,
// bias-trick epilogue. State double-buffered in LDS [buf][KB=8][el=128][16B].
// Round-10 delta vs round 6: operand tuples use UNDEF upper halves
// (fp4 fmt reads regs 0-3 only; proven correct in round 7) — removes ~160
// zero-fill v_movs per wave-round.
__global__ __launch_bounds__(512, 4) void hash4(const uint32_t* __restrict__ wpk,
                                                const float* __restrict__ nf,
                                                const float* __restrict__ sta,
                                                float* __restrict__ out) {
  __shared__ uint8_t T[2][8][128][16];  // 32 KB
  const int t = threadIdx.x;
  const int wv = __builtin_amdgcn_readfirstlane(t >> 6);  // m-tile 0..7
  const int lane = t & 63;
  const int l31 = lane & 31;
  const int lh = lane >> 5;
  const int el0 = blockIdx.x * 128;

  // ---- initial pack: f32 -> sigma-ordered fp4 nibbles (4 logical k per u16) ----
#pragma unroll
  for (int i = 0; i < 16; ++i) {
    unsigned flat = (unsigned)i * 512u + t;  // float4 idx in 128x256 slab
    unsigned el = flat >> 6, k4 = flat & 63u;
    float4 f = ((const float4*)(sta + (size_t)el0 * 256))[flat];
    uint32_t v = ((f.x != 0.f) ? 0x2u : 0u) | ((f.y != 0.f) ? 0x20u : 0u) |
                 ((f.z != 0.f) ? 0x200u : 0u) | ((f.w != 0.f) ? 0x2000u : 0u);
    unsigned KB = k4 >> 3, k4c = k4 & 7u;
    unsigned byteoff = (k4c & 1u) * 8u + 2u * (k4c >> 1);  // sigma^-1 of 4 rows
    *(uint16_t*)&T[0][KB][el][byteoff] = (uint16_t)v;
  }
  __syncthreads();

  // prefetch round-0 A fragments + noise C-init
  v4i ap[4];
  {
    const uint32_t* wb = wpk + ((wv * 4) << 8);
#pragma unroll
    for (int ks = 0; ks < 4; ++ks) ap[ks] = *(const v4i*)(wb + ks * 256 + lane * 4);
  }
  v16f NZ = *(const v16f*)(nf + (wv * 2 + lh) * 16);

  for (int r = 0; r < ROUNDS; ++r) {
    const int rb = r & 1, nx = rb ^ 1;
    v16f acc[4];
#pragma unroll
    for (int ks = 0; ks < 4; ++ks) {
      v8i A8 = __builtin_shufflevector(ap[ks], ap[ks], 0, 1, 2, 3, -1, -1, -1, -1);
      const int kb = 2 * ks + lh;
#pragma unroll
      for (int tn = 0; tn < 4; ++tn) {
        v4i b4 = *(const v4i*)&T[rb][kb][tn * 32 + l31][0];  // conflict-free b128
        v8i B8 = __builtin_shufflevector(b4, b4, 0, 1, 2, 3, -1, -1, -1, -1);
        acc[tn] = __builtin_amdgcn_mfma_scale_f32_32x32x64_f8f6f4(
            A8, B8, (ks == 0) ? NZ : acc[tn], 4, 4, 0, 127, 0, 127);
      }
    }

    // prefetch next round's A + noise (r=63 wraps to 0 -> no OOB, dead value)
    {
      const int rn = (r + 1) & 63;
      const uint32_t* wb = wpk + (((rn * 8 + wv) * 4) << 8);
#pragma unroll
      for (int ks = 0; ks < 4; ++ks) ap[ks] = *(const v4i*)(wb + ks * 256 + lane * 4);
      NZ = *(const v16f*)(nf + ((rn * 8 + wv) * 2 + lh) * 16);
    }

    // epilogue: bias trick puts integer LSB at bit 1 == fp4 "+1" nibble bit.
    // (acc+noise) in [-256,257]; +1.5*2^22 stays in [2^22,2^23): exact, ulp=0.5.
#pragma unroll
    for (int tn = 0; tn < 4; ++tn) {
      uint32_t lo = 0, hi = 0;
#pragma unroll
      for (int j = 7; j >= 0; --j)
        lo = (lo << 4) | (__builtin_bit_cast(uint32_t, acc[tn][j] + 6291456.0f) & 2u);
#pragma unroll
      for (int j = 15; j >= 8; --j)
        hi = (hi << 4) | (__builtin_bit_cast(uint32_t, acc[tn][j] + 6291456.0f) & 2u);
      *(uint2*)&T[nx][wv][tn * 32 + l31][lh * 8] = make_uint2(lo, hi);
    }

    __syncthreads();  // single barrier/round (double-buffered state)
  }

  // ---- final unpack: buf 0 holds the round-63 output ----
#pragma unroll
  for (int i = 0; i < 16; ++i) {
    unsigned flat = (unsigned)i * 512u + t;
    unsigned el = flat >> 6, k4 = flat & 63u;
    unsigned KB = k4 >> 3, k4c = k4 & 7u;
    unsigned byteoff = (k4c & 1u) * 8u + 2u * (k4c >> 1);
    uint32_t v = *(const uint16_t*)&T[0][KB][el][byteoff];
    float4 o = make_float4((float)((v >> 1) & 1u), (float)((v >> 5) & 1u),
                           (float)((v >> 9) & 1u), (float)((v >> 13) & 1u));
    ((float4*)(out + (size_t)el0 * 256))[flat] = o;
  }
}

extern "C" void kernel_launch(void* const* d_in, const int* in_sizes, int n_in,
                              void* d_out, int out_size, void* d_ws, size_t ws_size,
                              hipStream_t stream) {
  const float* sta = (const float*)d_in[0];  // [B, HIDDEN]
  const float* mat = (const float*)d_in[1];  // [ROUNDS, HIDDEN, HIDDEN]
  const float* noi = (const float*)d_in[2];  // [ROUNDS, HIDDEN]
  uint8_t* wsb = (uint8_t*)d_ws;             // needs ~2.07 MB

  pack_w4<<<576, 256, 0, stream>>>(mat, noi, (uint32_t*)wsb,
                                   (float*)(wsb + WPK_BYTES));
  hash4<<<512, 512, 0, stream>>>((const uint32_t*)wsb,
                                 (const float*)(wsb + WPK_BYTES), sta,
                                 (float*)d_out);
}